// Round 12
// baseline (70.122 us; speedup 1.0000x reference)
//
#include <hip/hip_runtime.h>

#define RADIUS 5
#define TILEX  16                   // output px per block in x
#define TILEY  16                   // output px per block in y
#define HX     (TILEX + 2*RADIUS)   // 26
#define HY     (TILEY + 2*RADIUS)   // 26
#define HPITCH 14                   // half-col pitch: row shift 56 words = 24 mod 32
                                    // -> h-quarter rows hit bank starts {0,24,16,8} (uniform)
#define H      256
#define W      256

// exp2-folded Mahalanobis coefficients kappa = -0.5*log2(e)*sigma_inv:
// ch0-1 (sigma 10.0), ch2-4 (0.02), ch5-7 (0.1)
#define KA (-0.072134752f)
#define KB (-36.06737602f)
#define KC (-7.213475204f)

typedef float v2f __attribute__((ext_vector_type(2)));

struct Center { v2f h01, h23, h45, h67; float phic; };

// Quadratic expansion, packed-fp32 form: t = P.w + pg + sum h_i*g_i computed as
// 4 v_pk_fma_f32 + adds; accumulates as 2 v_pk_fma_f32. pg carries the row-gate
// bias (-1000 -> exp2 = +0.0 exactly, so gated accums are exact no-ops).
__device__ __forceinline__ void accum(const float4 A, const float4 G, const float4 P,
                                      const Center& C, const float pg,
                                      v2f& swx, v2f& syz) {
    v2f t2;  t2.x = P.w + pg; t2.y = 0.f;
    v2f a01; a01.x = A.x; a01.y = A.y;
    v2f a23; a23.x = A.z; a23.y = A.w;
    v2f g01; g01.x = G.x; g01.y = G.y;
    v2f g23; g23.x = G.z; g23.y = G.w;
    t2 = __builtin_elementwise_fma(C.h01, a01, t2);
    t2 = __builtin_elementwise_fma(C.h23, a23, t2);
    t2 = __builtin_elementwise_fma(C.h45, g01, t2);
    t2 = __builtin_elementwise_fma(C.h67, g23, t2);
    const float w = __builtin_amdgcn_exp2f(t2.x + t2.y);
    v2f w2;  w2.x = w;   w2.y = w;
    v2f m0;  m0.x = 1.f; m0.y = P.x;
    v2f m1;  m1.x = P.y; m1.y = P.z;
    swx = __builtin_elementwise_fma(w2, m0, swx);   // (sum_w, acc_x)
    syz = __builtin_elementwise_fma(w2, m1, syz);   // (acc_y, acc_z)
}

// R12 = R11 math, re-tiled to 16x16 with 256-thread blocks and grid 512
// (2 blocks/CU = two independent barrier domains: one block computes while
// the other stages -> hides the exposed staging phase).
// block (8,4,8): threadIdx.x = px-pair x (lane bits 0-2), threadIdx.y =
// row-quarter h (lane bits 3-4 -> shfl_xor(8/16)), threadIdx.z = y-quad.
// Each thread: 2x2 px; 12 halo rows split exactly 3/3/3/3 across h.
__global__ __launch_bounds__(256, 2) void jbf_kernel(
    const float* __restrict__ image,     // (B,3,H,W)
    const float* __restrict__ guidance,  // (B,8,H,W)
    float* __restrict__ out)             // (B,3,H,W)
{
    __shared__ float4 g0e[HY * HPITCH], g0o[HY * HPITCH];  // guidance ch0-3
    __shared__ float4 g1e[HY * HPITCH], g1o[HY * HPITCH];  // guidance ch4-7
    __shared__ float4 ime[HY * HPITCH], imo[HY * HPITCH];  // image ch0-2 + phi

    const int b       = blockIdx.z;
    const int tile_x0 = blockIdx.x * TILEX;
    const int tile_y0 = blockIdx.y * TILEY;
    const int txp     = threadIdx.x;        // 0..7  (lane bits 0-2)
    const int h       = threadIdx.y;        // 0..3  (lane bits 3-4)
    const int typ     = threadIdx.z;        // 0..7
    const int tid     = (typ * 4 + h) * 8 + txp;

    const float* gbase = guidance + (size_t)b * 8 * H * W;
    const float* ibase = image    + (size_t)b * 3 * H * W;

    // ---- stage 26x26 halo (reflect) into even/odd interleaved LDS ----
    for (int idx = tid; idx < HX * HY; idx += 256) {
        const int ly = idx / HX;
        const int lx = idx - ly * HX;
        int gy = tile_y0 - RADIUS + ly;
        int gx = tile_x0 - RADIUS + lx;
        gy = (gy < 0) ? -gy : ((gy >= H) ? 2 * (H - 1) - gy : gy);
        gx = (gx < 0) ? -gx : ((gx >= W) ? 2 * (W - 1) - gx : gx);
        const int off = gy * W + gx;
        const int l   = ly * HPITCH + (lx >> 1);
        const float4 v0 = make_float4(gbase[0*H*W+off], gbase[1*H*W+off],
                                      gbase[2*H*W+off], gbase[3*H*W+off]);
        const float4 v1 = make_float4(gbase[4*H*W+off], gbase[5*H*W+off],
                                      gbase[6*H*W+off], gbase[7*H*W+off]);
        const float phi = KA * (v0.x*v0.x + v0.y*v0.y)
                        + KB * (v0.z*v0.z + v0.w*v0.w + v1.x*v1.x)
                        + KC * (v1.y*v1.y + v1.z*v1.z + v1.w*v1.w);
        const float4 vi = make_float4(ibase[0*H*W+off], ibase[1*H*W+off],
                                      ibase[2*H*W+off], phi);
        if (lx & 1) { g0o[l] = v0; g1o[l] = v1; imo[l] = vi; }
        else        { g0e[l] = v0; g1e[l] = v1; ime[l] = vi; }
    }
    __syncthreads();

    // centers: x0 = halo col 2txp+5 (odd, idx txp+2), x1 = 2txp+6 (even, txp+3)
    //          y0 = halo row 2typ+5, y1 = 2typ+6
    Center c[2][2];
    #pragma unroll
    for (int cy = 0; cy < 2; ++cy) {
        const int row = (2 * typ + 5 + cy) * HPITCH;
        #pragma unroll
        for (int cx = 0; cx < 2; ++cx) {
            const int ci = row + txp + 2 + cx;
            const float4 gA = cx ? g0e[ci] : g0o[ci];
            const float4 gB = cx ? g1e[ci] : g1o[ci];
            const float4 pv = cx ? ime[ci] : imo[ci];
            c[cx][cy].h01.x = -2.f*KA*gA.x;  c[cx][cy].h01.y = -2.f*KA*gA.y;
            c[cx][cy].h23.x = -2.f*KB*gA.z;  c[cx][cy].h23.y = -2.f*KB*gA.w;
            c[cx][cy].h45.x = -2.f*KB*gB.x;  c[cx][cy].h45.y = -2.f*KC*gB.y;
            c[cx][cy].h67.x = -2.f*KC*gB.z;  c[cx][cy].h67.y = -2.f*KC*gB.w;
            c[cx][cy].phic  = pv.w;
        }
    }

    v2f swx[2][2], syz[2][2];
    #pragma unroll
    for (int cx = 0; cx < 2; ++cx)
        #pragma unroll
        for (int cy = 0; cy < 2; ++cy) {
            swx[cx][cy].x = 0.f; swx[cx][cy].y = 0.f;
            syz[cx][cy].x = 0.f; syz[cx][cy].y = 0.f;
        }

    // quarter h handles halo rows r = h, h+4, h+8 of the quad's 12-row union.
    // Row-gate folded into exp2 arg: pg = phic + (serves ? 0 : -1000).
    #pragma unroll
    for (int i = 0; i < 3; ++i) {
        const int r  = 4 * i + h;
        const int rb = (2 * typ + r) * HPITCH + txp;
        const float b0 = (r <= 10) ? 0.0f : -1000.0f;   // serves y0?
        const float b1 = (r >= 1)  ? 0.0f : -1000.0f;   // serves y1?
        const float pg00 = c[0][0].phic + b0, pg01 = c[0][1].phic + b1;
        const float pg10 = c[1][0].phic + b0, pg11 = c[1][1].phic + b1;
        #pragma unroll
        for (int k = 0; k <= 5; ++k) {
            {   // EVEN columns: serve x0 (all k), x1 (k>=1)
                const float4 A = g0e[rb + k], G = g1e[rb + k], P = ime[rb + k];
                accum(A, G, P, c[0][0], pg00, swx[0][0], syz[0][0]);
                accum(A, G, P, c[0][1], pg01, swx[0][1], syz[0][1]);
                if (k >= 1) {
                    accum(A, G, P, c[1][0], pg10, swx[1][0], syz[1][0]);
                    accum(A, G, P, c[1][1], pg11, swx[1][1], syz[1][1]);
                }
            }
            {   // ODD columns: serve x0 (k<=4), x1 (all k)
                const float4 A = g0o[rb + k], G = g1o[rb + k], P = imo[rb + k];
                if (k <= 4) {
                    accum(A, G, P, c[0][0], pg00, swx[0][0], syz[0][0]);
                    accum(A, G, P, c[0][1], pg01, swx[0][1], syz[0][1]);
                }
                accum(A, G, P, c[1][0], pg10, swx[1][0], syz[1][0]);
                accum(A, G, P, c[1][1], pg11, swx[1][1], syz[1][1]);
            }
        }
    }

    // combine row-quarter partials: butterfly over lane bits 3-4 (h)
    #pragma unroll
    for (int cx = 0; cx < 2; ++cx)
        #pragma unroll
        for (int cy = 0; cy < 2; ++cy) {
            swx[cx][cy].x += __shfl_xor(swx[cx][cy].x, 8);
            swx[cx][cy].x += __shfl_xor(swx[cx][cy].x, 16);
            swx[cx][cy].y += __shfl_xor(swx[cx][cy].y, 8);
            swx[cx][cy].y += __shfl_xor(swx[cx][cy].y, 16);
            syz[cx][cy].x += __shfl_xor(syz[cx][cy].x, 8);
            syz[cx][cy].x += __shfl_xor(syz[cx][cy].x, 16);
            syz[cx][cy].y += __shfl_xor(syz[cx][cy].y, 8);
            syz[cx][cy].y += __shfl_xor(syz[cx][cy].y, 16);
        }

    if (h == 0) {
        // sum_w >= ~1 (center weight ~ 1); reference clip(1e-10) is a no-op
        const size_t base = (size_t)b * 3 * H * W
                          + (size_t)(tile_y0 + 2 * typ) * W + (tile_x0 + 2 * txp);
        #pragma unroll
        for (int cy = 0; cy < 2; ++cy) {
            const float i0 = 1.0f / swx[0][cy].x;
            const float i1 = 1.0f / swx[1][cy].x;
            float2* __restrict__ o2 = (float2*)(out + base + (size_t)cy * W);
            o2[0]           = make_float2(swx[0][cy].y * i0, swx[1][cy].y * i1);
            o2[(H*W) / 2]   = make_float2(syz[0][cy].x * i0, syz[1][cy].x * i1);
            o2[(2*H*W) / 2] = make_float2(syz[0][cy].y * i0, syz[1][cy].y * i1);
        }
    }
}

extern "C" void kernel_launch(void* const* d_in, const int* in_sizes, int n_in,
                              void* d_out, int out_size, void* d_ws, size_t ws_size,
                              hipStream_t stream) {
    const float* image    = (const float*)d_in[0];
    const float* guidance = (const float*)d_in[1];
    float* out            = (float*)d_out;

    const int B = in_sizes[0] / (3 * H * W);   // = 2
    dim3 grid(W / TILEX, H / TILEY, B);        // 16 x 16 x 2 = 512 blocks (2/CU)
    dim3 block(8, 4, 8);                       // 256 threads = 4 waves
    hipLaunchKernelGGL(jbf_kernel, grid, block, 0, stream, image, guidance, out);
}

// Round 13
// 67.147 us; speedup vs baseline: 1.0443x; 1.0443x over previous
//
#include <hip/hip_runtime.h>

#define RADIUS 5
#define TILEX  32                   // output px per block in x
#define TILEY  16                   // output px per block in y
#define HX     (TILEX + 2*RADIUS)   // 42
#define HY     (TILEY + 2*RADIUS)   // 26
#define HPITCH 22                   // half-col pitch: row shift 88 words = 24 mod 32
                                    // -> h-quarter rows hit bank starts {0,24,16,8} (uniform)
#define H      256
#define W      256

// exp2-folded Mahalanobis coefficients kappa = -0.5*log2(e)*sigma_inv:
// ch0-1 (sigma 10.0), ch2-4 (0.02), ch5-7 (0.1)
#define KA (-0.072134752f)
#define KB (-36.06737602f)
#define KC (-7.213475204f)

typedef float v2f __attribute__((ext_vector_type(2)));

struct Center { v2f h01, h23, h45, h67; float phic; };

// Quadratic expansion, packed-fp32 form: t = P.w + pg + sum h_i*g_i computed as
// 4 v_pk_fma_f32 + adds; accumulates as 2 v_pk_fma_f32. pg carries the row-gate
// bias (-1000 -> exp2 = +0.0 exactly, so gated accums are exact no-ops).
__device__ __forceinline__ void accum(const float4 A, const float4 G, const float4 P,
                                      const Center& C, const float pg,
                                      v2f& swx, v2f& syz) {
    v2f t2;  t2.x = P.w + pg; t2.y = 0.f;
    v2f a01; a01.x = A.x; a01.y = A.y;
    v2f a23; a23.x = A.z; a23.y = A.w;
    v2f g01; g01.x = G.x; g01.y = G.y;
    v2f g23; g23.x = G.z; g23.y = G.w;
    t2 = __builtin_elementwise_fma(C.h01, a01, t2);
    t2 = __builtin_elementwise_fma(C.h23, a23, t2);
    t2 = __builtin_elementwise_fma(C.h45, g01, t2);
    t2 = __builtin_elementwise_fma(C.h67, g23, t2);
    const float w = __builtin_amdgcn_exp2f(t2.x + t2.y);
    v2f w2;  w2.x = w;   w2.y = w;
    v2f m0;  m0.x = 1.f; m0.y = P.x;
    v2f m1;  m1.x = P.y; m1.y = P.z;
    swx = __builtin_elementwise_fma(w2, m0, swx);   // (sum_w, acc_x)
    syz = __builtin_elementwise_fma(w2, m1, syz);   // (acc_y, acc_z)
}

// R13 = R11 (best, kernel ~11.1us) + XCD-aware block swizzle.
// Flat grid of 256 blocks; id%8 = XCD under round-robin dispatch. Each XCD
// gets a contiguous 2-tile-col x 16-tile-row region of one batch image, so
// halo re-reads between adjacent tiles hit that XCD's L2 instead of HBM
// (L2/L3 are cold every timed call: the harness's 268MB ws-poison evicts both).
// block (16,4,8): txp = px-pair x (lane bits 0-3), h = row-quarter (lane bits
// 4-5 -> shfl_xor(16/32) combine), typ = y-quad (wave id). 2x2 px per thread.
__global__ __launch_bounds__(512, 2) void jbf_kernel(
    const float* __restrict__ image,     // (B,3,H,W)
    const float* __restrict__ guidance,  // (B,8,H,W)
    float* __restrict__ out)             // (B,3,H,W)
{
    __shared__ float4 g0e[HY * HPITCH], g0o[HY * HPITCH];  // guidance ch0-3
    __shared__ float4 g1e[HY * HPITCH], g1o[HY * HPITCH];  // guidance ch4-7
    __shared__ float4 ime[HY * HPITCH], imo[HY * HPITCH];  // image ch0-2 + phi

    // XCD swizzle: c = id%8 (XCD), r = id/8 (rank within XCD).
    // XCDs 0-3 -> batch 0, 4-7 -> batch 1; XCD owns tile-cols {2m, 2m+1}
    // (m = c%4) over all 16 tile-rows: bx = 2m + (r&1), by = r>>1.
    const int id = blockIdx.x;
    const int c_xcd = id & 7;
    const int r_rnk = id >> 3;               // 0..31
    const int b       = c_xcd >> 2;
    const int tile_x0 = (((c_xcd & 3) << 1) | (r_rnk & 1)) * TILEX;
    const int tile_y0 = (r_rnk >> 1) * TILEY;

    const int txp = threadIdx.x;             // 0..15 (lane bits 0-3)
    const int h   = threadIdx.y;             // 0..3  (lane bits 4-5)
    const int typ = threadIdx.z;             // 0..7  (wave id)
    const int tid = (typ * 4 + h) * 16 + txp;

    const float* gbase = guidance + (size_t)b * 8 * H * W;
    const float* ibase = image    + (size_t)b * 3 * H * W;

    // ---- stage 42x26 halo (reflect) into even/odd interleaved LDS ----
    for (int idx = tid; idx < HX * HY; idx += 512) {
        const int ly = idx / HX;
        const int lx = idx - ly * HX;
        int gy = tile_y0 - RADIUS + ly;
        int gx = tile_x0 - RADIUS + lx;
        gy = (gy < 0) ? -gy : ((gy >= H) ? 2 * (H - 1) - gy : gy);
        gx = (gx < 0) ? -gx : ((gx >= W) ? 2 * (W - 1) - gx : gx);
        const int off = gy * W + gx;
        const int l   = ly * HPITCH + (lx >> 1);
        const float4 v0 = make_float4(gbase[0*H*W+off], gbase[1*H*W+off],
                                      gbase[2*H*W+off], gbase[3*H*W+off]);
        const float4 v1 = make_float4(gbase[4*H*W+off], gbase[5*H*W+off],
                                      gbase[6*H*W+off], gbase[7*H*W+off]);
        const float phi = KA * (v0.x*v0.x + v0.y*v0.y)
                        + KB * (v0.z*v0.z + v0.w*v0.w + v1.x*v1.x)
                        + KC * (v1.y*v1.y + v1.z*v1.z + v1.w*v1.w);
        const float4 vi = make_float4(ibase[0*H*W+off], ibase[1*H*W+off],
                                      ibase[2*H*W+off], phi);
        if (lx & 1) { g0o[l] = v0; g1o[l] = v1; imo[l] = vi; }
        else        { g0e[l] = v0; g1e[l] = v1; ime[l] = vi; }
    }
    __syncthreads();

    // centers: x0 = halo col 2txp+5 (odd, idx txp+2), x1 = 2txp+6 (even, txp+3)
    //          y0 = halo row 2typ+5, y1 = 2typ+6
    Center c[2][2];
    #pragma unroll
    for (int cy = 0; cy < 2; ++cy) {
        const int row = (2 * typ + 5 + cy) * HPITCH;
        #pragma unroll
        for (int cx = 0; cx < 2; ++cx) {
            const int ci = row + txp + 2 + cx;
            const float4 gA = cx ? g0e[ci] : g0o[ci];
            const float4 gB = cx ? g1e[ci] : g1o[ci];
            const float4 pv = cx ? ime[ci] : imo[ci];
            c[cx][cy].h01.x = -2.f*KA*gA.x;  c[cx][cy].h01.y = -2.f*KA*gA.y;
            c[cx][cy].h23.x = -2.f*KB*gA.z;  c[cx][cy].h23.y = -2.f*KB*gA.w;
            c[cx][cy].h45.x = -2.f*KB*gB.x;  c[cx][cy].h45.y = -2.f*KC*gB.y;
            c[cx][cy].h67.x = -2.f*KC*gB.z;  c[cx][cy].h67.y = -2.f*KC*gB.w;
            c[cx][cy].phic  = pv.w;
        }
    }

    v2f swx[2][2], syz[2][2];
    #pragma unroll
    for (int cx = 0; cx < 2; ++cx)
        #pragma unroll
        for (int cy = 0; cy < 2; ++cy) {
            swx[cx][cy].x = 0.f; swx[cx][cy].y = 0.f;
            syz[cx][cy].x = 0.f; syz[cx][cy].y = 0.f;
        }

    // quarter h handles halo rows r = h, h+4, h+8 of the quad's 12-row union.
    // Row-gate folded into exp2 arg: pg = phic + (serves ? 0 : -1000).
    #pragma unroll
    for (int i = 0; i < 3; ++i) {
        const int r  = 4 * i + h;
        const int rb = (2 * typ + r) * HPITCH + txp;
        const float b0 = (r <= 10) ? 0.0f : -1000.0f;   // serves y0?
        const float b1 = (r >= 1)  ? 0.0f : -1000.0f;   // serves y1?
        const float pg00 = c[0][0].phic + b0, pg01 = c[0][1].phic + b1;
        const float pg10 = c[1][0].phic + b0, pg11 = c[1][1].phic + b1;
        #pragma unroll
        for (int k = 0; k <= 5; ++k) {
            {   // EVEN columns: serve x0 (all k), x1 (k>=1)
                const float4 A = g0e[rb + k], G = g1e[rb + k], P = ime[rb + k];
                accum(A, G, P, c[0][0], pg00, swx[0][0], syz[0][0]);
                accum(A, G, P, c[0][1], pg01, swx[0][1], syz[0][1]);
                if (k >= 1) {
                    accum(A, G, P, c[1][0], pg10, swx[1][0], syz[1][0]);
                    accum(A, G, P, c[1][1], pg11, swx[1][1], syz[1][1]);
                }
            }
            {   // ODD columns: serve x0 (k<=4), x1 (all k)
                const float4 A = g0o[rb + k], G = g1o[rb + k], P = imo[rb + k];
                if (k <= 4) {
                    accum(A, G, P, c[0][0], pg00, swx[0][0], syz[0][0]);
                    accum(A, G, P, c[0][1], pg01, swx[0][1], syz[0][1]);
                }
                accum(A, G, P, c[1][0], pg10, swx[1][0], syz[1][0]);
                accum(A, G, P, c[1][1], pg11, swx[1][1], syz[1][1]);
            }
        }
    }

    // combine row-quarter partials: butterfly over lane bits 4-5 (h)
    #pragma unroll
    for (int cx = 0; cx < 2; ++cx)
        #pragma unroll
        for (int cy = 0; cy < 2; ++cy) {
            swx[cx][cy].x += __shfl_xor(swx[cx][cy].x, 16);
            swx[cx][cy].x += __shfl_xor(swx[cx][cy].x, 32);
            swx[cx][cy].y += __shfl_xor(swx[cx][cy].y, 16);
            swx[cx][cy].y += __shfl_xor(swx[cx][cy].y, 32);
            syz[cx][cy].x += __shfl_xor(syz[cx][cy].x, 16);
            syz[cx][cy].x += __shfl_xor(syz[cx][cy].x, 32);
            syz[cx][cy].y += __shfl_xor(syz[cx][cy].y, 16);
            syz[cx][cy].y += __shfl_xor(syz[cx][cy].y, 32);
        }

    if (h == 0) {
        // sum_w >= ~1 (center weight ~ 1); reference clip(1e-10) is a no-op
        const size_t base = (size_t)b * 3 * H * W
                          + (size_t)(tile_y0 + 2 * typ) * W + (tile_x0 + 2 * txp);
        #pragma unroll
        for (int cy = 0; cy < 2; ++cy) {
            const float i0 = 1.0f / swx[0][cy].x;
            const float i1 = 1.0f / swx[1][cy].x;
            float2* __restrict__ o2 = (float2*)(out + base + (size_t)cy * W);
            o2[0]           = make_float2(swx[0][cy].y * i0, swx[1][cy].y * i1);
            o2[(H*W) / 2]   = make_float2(syz[0][cy].x * i0, syz[1][cy].x * i1);
            o2[(2*H*W) / 2] = make_float2(syz[0][cy].y * i0, syz[1][cy].y * i1);
        }
    }
}

extern "C" void kernel_launch(void* const* d_in, const int* in_sizes, int n_in,
                              void* d_out, int out_size, void* d_ws, size_t ws_size,
                              hipStream_t stream) {
    const float* image    = (const float*)d_in[0];
    const float* guidance = (const float*)d_in[1];
    float* out            = (float*)d_out;

    // flat grid: in-kernel XCD swizzle maps id -> (batch, tile). 256 = 8x16x2.
    dim3 grid(256, 1, 1);
    dim3 block(16, 4, 8);                      // 512 threads = 8 waves
    hipLaunchKernelGGL(jbf_kernel, grid, block, 0, stream, image, guidance, out);
}